// Round 3
// baseline (1021.526 us; speedup 1.0000x reference)
//
#include <hip/hip_runtime.h>
#include <hip/hip_bf16.h>
#include <math.h>

typedef __attribute__((ext_vector_type(8))) __bf16 bf16x8;
typedef __attribute__((ext_vector_type(4))) float f32x4;

#define LSTR 40   // LDS row stride (elements), pads 32-wide K tiles to kill bank conflicts

// ---------------- GEMM: C[M,N] = A[M,K] @ Bt[N,K]^T, bf16 in, fp32 accum, bf16 out ----------
// M%128==0, N%128==0, K%32==0, lda=K, ldbt=K, ldc=N
__global__ __launch_bounds__(256) void gemm_bt(const __bf16* __restrict__ A,
                                               const __bf16* __restrict__ Bt,
                                               __bf16* __restrict__ C,
                                               int M, int N, int K) {
    __shared__ __bf16 As[128 * LSTR];
    __shared__ __bf16 Bs[128 * LSTR];
    const int t = threadIdx.x;
    const int lane = t & 63;
    const int wid = t >> 6;
    const int wm = (wid >> 1) << 6;
    const int wn = (wid & 1) << 6;
    const int bm = blockIdx.x * 128;
    const int bn = blockIdx.y * 128;

    const int lr = t >> 2;        // 0..63
    const int lc = (t & 3) << 3;  // 0,8,16,24

    f32x4 acc[4][4];
#pragma unroll
    for (int i = 0; i < 4; i++)
#pragma unroll
        for (int j = 0; j < 4; j++) acc[i][j] = (f32x4){0.f, 0.f, 0.f, 0.f};

    const int m16 = lane & 15;
    const int k8 = (lane >> 4) << 3;

    for (int k0 = 0; k0 < K; k0 += 32) {
        bf16x8 a0 = *(const bf16x8*)(A + (size_t)(bm + lr) * K + k0 + lc);
        bf16x8 a1 = *(const bf16x8*)(A + (size_t)(bm + lr + 64) * K + k0 + lc);
        bf16x8 b0 = *(const bf16x8*)(Bt + (size_t)(bn + lr) * K + k0 + lc);
        bf16x8 b1 = *(const bf16x8*)(Bt + (size_t)(bn + lr + 64) * K + k0 + lc);
        __syncthreads();
        *(bf16x8*)(As + lr * LSTR + lc) = a0;
        *(bf16x8*)(As + (lr + 64) * LSTR + lc) = a1;
        *(bf16x8*)(Bs + lr * LSTR + lc) = b0;
        *(bf16x8*)(Bs + (lr + 64) * LSTR + lc) = b1;
        __syncthreads();
        bf16x8 af[4], bfr[4];
#pragma unroll
        for (int i = 0; i < 4; i++) {
            af[i] = *(const bf16x8*)(As + (wm + 16 * i + m16) * LSTR + k8);
            bfr[i] = *(const bf16x8*)(Bs + (wn + 16 * i + m16) * LSTR + k8);
        }
#pragma unroll
        for (int i = 0; i < 4; i++)
#pragma unroll
            for (int j = 0; j < 4; j++)
                acc[i][j] = __builtin_amdgcn_mfma_f32_16x16x32_bf16(af[i], bfr[j], acc[i][j], 0, 0, 0);
    }
    const int r4 = (lane >> 4) << 2;
#pragma unroll
    for (int i = 0; i < 4; i++) {
#pragma unroll
        for (int j = 0; j < 4; j++) {
            int col = bn + wn + 16 * j + m16;
#pragma unroll
            for (int r = 0; r < 4; r++) {
                int row = bm + wm + 16 * i + r4 + r;
                C[(size_t)row * N + col] = (__bf16)acc[i][j][r];
            }
        }
    }
}

// ---------------- x (fp32) -> padded bf16 [Mpad,64], zeros outside ----------------
__global__ void pack_x_k(const float* __restrict__ x, __bf16* __restrict__ xp, int rows_real) {
    int i = blockIdx.x * 256 + threadIdx.x;
    int n = i >> 6, c = i & 63;
    float v = 0.f;
    if (n < rows_real && c < 50) v = x[n * 50 + c];
    xp[(size_t)n * 64 + c] = (__bf16)v;
}

// ---------------- transpose+pad: W[K,N] fp32 -> WT[Np,Kp] bf16 (zeros outside) -----------
__global__ void transpose_pad_k(const float* __restrict__ W, __bf16* __restrict__ WT,
                                int K, int N, int Kp, int Np) {
    __shared__ float tile[32][33];
    int bx = blockIdx.x, by = blockIdx.y;
    int tx = threadIdx.x & 31, ty = threadIdx.x >> 5;  // 32 x 8
#pragma unroll
    for (int r = ty; r < 32; r += 8) {
        int k = by * 32 + r, n = bx * 32 + tx;
        float v = 0.f;
        if (k < K && n < N) v = W[(size_t)k * N + n];
        tile[r][tx] = v;
    }
    __syncthreads();
#pragma unroll
    for (int r = ty; r < 32; r += 8) {
        int n = bx * 32 + r, k = by * 32 + tx;
        if (n < Np && k < Kp) WT[(size_t)n * Kp + k] = (__bf16)tile[tx][r];
    }
}

// ---------------- edge_index dtype probe: 1 if int64 (odd int32 slots all zero) -----------
__global__ void probe_ei_k(const int* __restrict__ ei, int* __restrict__ flag) {
    if (blockIdx.x == 0 && threadIdx.x == 0) {
        int all0 = 1;
        for (int i = 0; i < 64; i++)
            if (ei[2 * i + 1] != 0) { all0 = 0; break; }
        *flag = all0;
    }
}

__device__ __forceinline__ int load_ei(const int* ei, int idx, int is64) {
    return is64 ? ei[2 * idx] : ei[idx];
}

// ---------------- CSR build (by dst, self-loops appended) ----------------
__global__ void hist_k(const int* __restrict__ ei, const int* __restrict__ flag,
                       int* __restrict__ cnt, int E, int Nn) {
    int e = blockIdx.x * 256 + threadIdx.x;
    if (e >= E + Nn) return;
    int is64 = *flag;
    int d = (e < E) ? load_ei(ei, E + e, is64) : (e - E);
    d = min(max(d, 0), Nn - 1);
    atomicAdd(&cnt[d], 1);
}

__global__ __launch_bounds__(1024) void scan_k(const int* __restrict__ cnt, int* __restrict__ row_ptr,
                                               int Nn, int total) {
    __shared__ int part[1024];
    int t = threadIdx.x;
    int chunk = (Nn + 1023) >> 10;
    int lo = t * chunk;
    int hi = lo + chunk; if (hi > Nn) hi = Nn; if (lo > Nn) lo = Nn;
    int s = 0;
    for (int i = lo; i < hi; i++) s += cnt[i];
    part[t] = s;
    __syncthreads();
    for (int off = 1; off < 1024; off <<= 1) {
        int v = (t >= off) ? part[t - off] : 0;
        __syncthreads();
        part[t] += v;
        __syncthreads();
    }
    int run = part[t] - s;
    for (int i = lo; i < hi; i++) { row_ptr[i] = run; run += cnt[i]; }
    if (t == 0) row_ptr[Nn] = total;
}

__global__ void fill_csr_k(const int* __restrict__ ei, const int* __restrict__ flag,
                           const int* __restrict__ row_ptr, int* __restrict__ cursor,
                           int* __restrict__ src_csr, int E, int Nn) {
    int e = blockIdx.x * 256 + threadIdx.x;
    if (e >= E + Nn) return;
    int is64 = *flag;
    int d = (e < E) ? load_ei(ei, E + e, is64) : (e - E);
    int s = (e < E) ? load_ei(ei, e, is64) : (e - E);
    d = min(max(d, 0), Nn - 1);
    s = min(max(s, 0), Nn - 1);
    int slot = row_ptr[d] + atomicAdd(&cursor[d], 1);
    src_csr[slot] = s;
}

// ---------------- per-(node,head) attention dots (a vectors fp32) ----------------
__global__ void alpha_k(const __bf16* __restrict__ XL, int ld, const float* __restrict__ a_src,
                        const float* __restrict__ a_dst, float* __restrict__ asrc,
                        float* __restrict__ adst, int Nn, int H, int C) {
    int gw = (blockIdx.x * 256 + threadIdx.x) >> 6;
    int lane = threadIdx.x & 63;
    if (gw >= Nn * H) return;
    int n = gw / H, h = gw - n * H;
    const __bf16* row = XL + (size_t)n * ld + h * C;
    const float* as = a_src + h * C;
    const float* ad = a_dst + h * C;
    float s = 0.f, d = 0.f;
    for (int c = lane; c < C; c += 64) {
        float v = (float)row[c];
        s += v * as[c];
        d += v * ad[c];
    }
#pragma unroll
    for (int off = 32; off; off >>= 1) {
        s += __shfl_down(s, off);
        d += __shfl_down(d, off);
    }
    if (lane == 0) { asrc[n * H + h] = s; adst[n * H + h] = d; }
}

// ---------------- per-node segment softmax -> edge weights (one wave per node) -----------
__global__ void attn_k(const int* __restrict__ row_ptr, const int* __restrict__ src_csr,
                       const float* __restrict__ asrc, const float* __restrict__ adst,
                       float* __restrict__ w, int Nn, int H) {
    int gw = (blockIdx.x * 256 + threadIdx.x) >> 6;
    int lane = threadIdx.x & 63;
    if (gw >= Nn) return;
    int n = gw;
    int base = row_ptr[n], deg = row_ptr[n + 1] - base;
    for (int h = 0; h < H; h++) {
        float ad = adst[n * H + h];
        float m = -1e30f;
        for (int s = lane; s < deg; s += 64) {
            float e = asrc[src_csr[base + s] * H + h] + ad;
            e = e > 0.f ? e : 0.2f * e;
            m = fmaxf(m, e);
        }
#pragma unroll
        for (int off = 1; off < 64; off <<= 1) m = fmaxf(m, __shfl_xor(m, off));
        float sum = 0.f;
        for (int s = lane; s < deg; s += 64) {
            float e = asrc[src_csr[base + s] * H + h] + ad;
            e = e > 0.f ? e : 0.2f * e;
            sum += __expf(e - m);
        }
#pragma unroll
        for (int off = 1; off < 64; off <<= 1) sum += __shfl_xor(sum, off);
        float inv = 1.f / (sum + 1e-16f);
        for (int s = lane; s < deg; s += 64) {
            float e = asrc[src_csr[base + s] * H + h] + ad;
            e = e > 0.f ? e : 0.2f * e;
            w[(size_t)(base + s) * H + h] = __expf(e - m) * inv;
        }
    }
}

// ------- weighted aggregation (concat layers): SK += agg + b + sb (biases fp32) ----------
__global__ __launch_bounds__(256) void aggregate_skip_k(const __bf16* __restrict__ XL, int ld,
                                                        const float* __restrict__ w,
                                                        const int* __restrict__ row_ptr,
                                                        const int* __restrict__ src_csr,
                                                        const float* __restrict__ bias,
                                                        const float* __restrict__ sb,
                                                        __bf16* __restrict__ SK, int H, int C) {
    int n = blockIdx.x;
    int t = threadIdx.x;
    float acc[4] = {0.f, 0.f, 0.f, 0.f};
    int hj[4];
#pragma unroll
    for (int j = 0; j < 4; j++) hj[j] = (t + 256 * j) / C;
    int base = row_ptr[n], end = row_ptr[n + 1];
    for (int s = base; s < end; s++) {
        int src = src_csr[s];
        const __bf16* xr = XL + (size_t)src * ld;
        const float* wp = w + (size_t)s * H;
#pragma unroll
        for (int j = 0; j < 4; j++) acc[j] += wp[hj[j]] * (float)xr[t + 256 * j];
    }
    size_t ro = (size_t)n * 1024;
#pragma unroll
    for (int j = 0; j < 4; j++) {
        int c = t + 256 * j;
        float v = acc[j] + bias[c] + sb[c] + (float)SK[ro + c];
        SK[ro + c] = (__bf16)v;
    }
}

// ---------------- layer-3 aggregation + head mean + bias -> fp32 out ----------------
__global__ __launch_bounds__(256) void aggregate_mean_k(const __bf16* __restrict__ XL, int ld,
                                                        const float* __restrict__ w,
                                                        const int* __restrict__ row_ptr,
                                                        const int* __restrict__ src_csr,
                                                        const float* __restrict__ b3,
                                                        float* __restrict__ out) {
    const int H = 6, C = 121, NC = 726;
    __shared__ float red[NC];
    int n = blockIdx.x;
    int t = threadIdx.x;
    float acc[3] = {0.f, 0.f, 0.f};
    int hj[3];
    bool val[3];
#pragma unroll
    for (int j = 0; j < 3; j++) {
        int c = t + 256 * j;
        val[j] = c < NC;
        hj[j] = val[j] ? c / C : 0;
    }
    int base = row_ptr[n], end = row_ptr[n + 1];
    for (int s = base; s < end; s++) {
        int src = src_csr[s];
        const __bf16* xr = XL + (size_t)src * ld;
        const float* wp = w + (size_t)s * H;
#pragma unroll
        for (int j = 0; j < 3; j++)
            if (val[j]) acc[j] += wp[hj[j]] * (float)xr[t + 256 * j];
    }
#pragma unroll
    for (int j = 0; j < 3; j++)
        if (val[j]) red[t + 256 * j] = acc[j];
    __syncthreads();
    if (t < C) {
        float s6 = 0.f;
#pragma unroll
        for (int h = 0; h < H; h++) s6 += red[h * C + t];
        out[(size_t)n * C + t] = s6 * (1.f / 6.f) + b3[t];
    }
}

// ---------------- LayerNorm + ELU (input already = agg + b + skip + sb) ----------------
__global__ __launch_bounds__(256) void ln_elu_k(const __bf16* __restrict__ in,
                                                const float* __restrict__ g,
                                                const float* __restrict__ be,
                                                __bf16* __restrict__ out, int rows_real) {
    const int D = 1024;
    int n = blockIdx.x;
    int t = threadIdx.x;
    size_t ro = (size_t)n * D;
    if (n >= rows_real) {
#pragma unroll
        for (int j = 0; j < 4; j++) out[ro + t + 256 * j] = (__bf16)0.f;
        return;
    }
    float v[4];
    float s = 0.f, q = 0.f;
#pragma unroll
    for (int j = 0; j < 4; j++) {
        int c = t + 256 * j;
        float a = (float)in[ro + c];
        v[j] = a;
        s += a;
        q += a * a;
    }
#pragma unroll
    for (int off = 32; off; off >>= 1) {
        s += __shfl_down(s, off);
        q += __shfl_down(q, off);
    }
    __shared__ float rs[8];
    int wid = t >> 6;
    if ((t & 63) == 0) { rs[wid] = s; rs[wid + 4] = q; }
    __syncthreads();
    s = rs[0] + rs[1] + rs[2] + rs[3];
    q = rs[4] + rs[5] + rs[6] + rs[7];
    float mu = s * (1.f / 1024.f);
    float var = q * (1.f / 1024.f) - mu * mu;
    float inv = rsqrtf(fmaxf(var, 0.f) + 1e-5f);
#pragma unroll
    for (int j = 0; j < 4; j++) {
        int c = t + 256 * j;
        float y = (v[j] - mu) * inv * g[c] + be[c];
        y = y > 0.f ? y : expm1f(y);
        out[ro + c] = (__bf16)y;
    }
}

extern "C" void kernel_launch(void* const* d_in, const int* in_sizes, int n_in,
                              void* d_out, int out_size, void* d_ws, size_t ws_size,
                              hipStream_t stream) {
    const float* x   = (const float*)d_in[0];
    const int*   ei  = (const int*)d_in[1];
    const float* W1  = (const float*)d_in[2];
    const float* as1 = (const float*)d_in[3];
    const float* ad1 = (const float*)d_in[4];
    const float* b1  = (const float*)d_in[5];
    const float* W2  = (const float*)d_in[6];
    const float* as2 = (const float*)d_in[7];
    const float* ad2 = (const float*)d_in[8];
    const float* b2  = (const float*)d_in[9];
    const float* W3  = (const float*)d_in[10];
    const float* as3 = (const float*)d_in[11];
    const float* ad3 = (const float*)d_in[12];
    const float* b3  = (const float*)d_in[13];
    const float* sW1 = (const float*)d_in[14];
    const float* sb1 = (const float*)d_in[15];
    const float* sW2 = (const float*)d_in[16];
    const float* sb2 = (const float*)d_in[17];
    const float* g1  = (const float*)d_in[18];
    const float* be1 = (const float*)d_in[19];
    const float* g2  = (const float*)d_in[20];
    const float* be2 = (const float*)d_in[21];
    float* out = (float*)d_out;

    const int Nn = 20000;
    const int E = in_sizes[1] / 2;     // 320000
    const int E2 = E + Nn;             // 340000
    const int Mpad = 20096;            // 157*128

    char* p = (char*)d_ws;
    auto alloc = [&](size_t bytes) {
        char* r = p;
        p += (bytes + 255) & ~(size_t)255;
        return r;
    };
    __bf16* W1pT  = (__bf16*)alloc((size_t)1024 * 64 * 2);
    __bf16* sW1T  = (__bf16*)alloc((size_t)1024 * 64 * 2);
    __bf16* W2T   = (__bf16*)alloc((size_t)1024 * 1024 * 2);
    __bf16* sW2T  = (__bf16*)alloc((size_t)1024 * 1024 * 2);
    __bf16* W3pT  = (__bf16*)alloc((size_t)768 * 1024 * 2);
    __bf16* xp    = (__bf16*)alloc((size_t)Mpad * 64 * 2);
    __bf16* XL    = (__bf16*)alloc((size_t)Mpad * 1024 * 2);
    __bf16* SK    = (__bf16*)alloc((size_t)Mpad * 1024 * 2);
    __bf16* H1    = (__bf16*)alloc((size_t)Mpad * 1024 * 2);
    float*  asrcb = (float*)alloc((size_t)Nn * 6 * 4);
    float*  adstb = (float*)alloc((size_t)Nn * 6 * 4);
    float*  wbuf  = (float*)alloc((size_t)E2 * 6 * 4);
    int*    rowp  = (int*)alloc((size_t)(Nn + 1) * 4);
    int*    cnt   = (int*)alloc((size_t)Nn * 4);
    int*    scsr  = (int*)alloc((size_t)E2 * 4);
    int*    eiflag= (int*)alloc(256);
    (void)ws_size; (void)n_in; (void)out_size;

    // ---- prep: fp32 -> bf16 packing / transposes ----
    pack_x_k<<<(Mpad * 64) / 256, 256, 0, stream>>>(x, xp, Nn);
    transpose_pad_k<<<dim3(32, 2), 256, 0, stream>>>(W1, W1pT, 50, 1024, 64, 1024);
    transpose_pad_k<<<dim3(32, 2), 256, 0, stream>>>(sW1, sW1T, 50, 1024, 64, 1024);
    transpose_pad_k<<<dim3(32, 32), 256, 0, stream>>>(W2, W2T, 1024, 1024, 1024, 1024);
    transpose_pad_k<<<dim3(32, 32), 256, 0, stream>>>(sW2, sW2T, 1024, 1024, 1024, 1024);
    transpose_pad_k<<<dim3(24, 32), 256, 0, stream>>>(W3, W3pT, 1024, 726, 1024, 768);

    // ---- CSR ----
    probe_ei_k<<<1, 64, 0, stream>>>(ei, eiflag);
    hipMemsetAsync(cnt, 0, (size_t)Nn * 4, stream);
    hist_k<<<(E2 + 255) / 256, 256, 0, stream>>>(ei, eiflag, cnt, E, Nn);
    scan_k<<<1, 1024, 0, stream>>>(cnt, rowp, Nn, E2);
    hipMemsetAsync(cnt, 0, (size_t)Nn * 4, stream);
    fill_csr_k<<<(E2 + 255) / 256, 256, 0, stream>>>(ei, eiflag, rowp, cnt, scsr, E, Nn);

    // ---- layer 1: 50 -> 4x256 concat ----
    gemm_bt<<<dim3(Mpad / 128, 8), 256, 0, stream>>>(xp, W1pT, XL, Mpad, 1024, 64);
    gemm_bt<<<dim3(Mpad / 128, 8), 256, 0, stream>>>(xp, sW1T, SK, Mpad, 1024, 64);
    alpha_k<<<(Nn * 4 * 64) / 256, 256, 0, stream>>>(XL, 1024, as1, ad1, asrcb, adstb, Nn, 4, 256);
    attn_k<<<(Nn + 3) / 4, 256, 0, stream>>>(rowp, scsr, asrcb, adstb, wbuf, Nn, 4);
    aggregate_skip_k<<<Nn, 256, 0, stream>>>(XL, 1024, wbuf, rowp, scsr, b1, sb1, SK, 4, 256);
    ln_elu_k<<<Mpad, 256, 0, stream>>>(SK, g1, be1, H1, Nn);

    // ---- layer 2: 1024 -> 4x256 concat ----
    gemm_bt<<<dim3(Mpad / 128, 8), 256, 0, stream>>>(H1, W2T, XL, Mpad, 1024, 1024);
    gemm_bt<<<dim3(Mpad / 128, 8), 256, 0, stream>>>(H1, sW2T, SK, Mpad, 1024, 1024);
    alpha_k<<<(Nn * 4 * 64) / 256, 256, 0, stream>>>(XL, 1024, as2, ad2, asrcb, adstb, Nn, 4, 256);
    attn_k<<<(Nn + 3) / 4, 256, 0, stream>>>(rowp, scsr, asrcb, adstb, wbuf, Nn, 4);
    aggregate_skip_k<<<Nn, 256, 0, stream>>>(XL, 1024, wbuf, rowp, scsr, b2, sb2, SK, 4, 256);
    ln_elu_k<<<Mpad, 256, 0, stream>>>(SK, g2, be2, H1, Nn);  // H1 := h2

    // ---- layer 3: 1024 -> 6x121, mean over heads ----
    gemm_bt<<<dim3(Mpad / 128, 6), 256, 0, stream>>>(H1, W3pT, XL, Mpad, 768, 1024);
    alpha_k<<<(Nn * 6 * 64) / 256, 256, 0, stream>>>(XL, 768, as3, ad3, asrcb, adstb, Nn, 6, 121);
    attn_k<<<(Nn + 3) / 4, 256, 0, stream>>>(rowp, scsr, asrcb, adstb, wbuf, Nn, 6);
    aggregate_mean_k<<<Nn, 256, 0, stream>>>(XL, 768, wbuf, rowp, scsr, b3, out);
}